// Round 14
// baseline (22.966 us; speedup 1.0000x reference)
//
#include <hip/hip_runtime.h>
#include <math.h>
#include <float.h>

#define BATCH 1024
#define DIM 128
#define EPSV 1e-12f
#define MARGIN 0.5f
#define INTRA_MARGIN 0.1f
#define LAMDA 0.5f

typedef __attribute__((ext_vector_type(8))) short s16x8;   // 8 bf16 (4 VGPRs)
typedef __attribute__((ext_vector_type(4))) float f32x4;   // MFMA C/D

__device__ __forceinline__ ushort f2bf(float f) {          // RNE fp32 -> bf16
    unsigned u = __float_as_uint(f);
    return (ushort)((u + 0x7fffu + ((u >> 16) & 1u)) >> 16);
}

// convert 8 fp32 -> bf16x8 fragment, accumulating sum-of-squares (exact fp32)
__device__ __forceinline__ s16x8 cvt8(float4 a, float4 b, float& ss) {
    s16x8 r;
    r[0] = (short)f2bf(a.x); ss = fmaf(a.x, a.x, ss);
    r[1] = (short)f2bf(a.y); ss = fmaf(a.y, a.y, ss);
    r[2] = (short)f2bf(a.z); ss = fmaf(a.z, a.z, ss);
    r[3] = (short)f2bf(a.w); ss = fmaf(a.w, a.w, ss);
    r[4] = (short)f2bf(b.x); ss = fmaf(b.x, b.x, ss);
    r[5] = (short)f2bf(b.y); ss = fmaf(b.y, b.y, ss);
    r[6] = (short)f2bf(b.z); ss = fmaf(b.z, b.z, ss);
    r[7] = (short)f2bf(b.w); ss = fmaf(b.w, b.w, ss);
    return r;
}

// async global->LDS, 16B per lane (dest = wave-uniform base + lane*16)
__device__ __forceinline__ void gl_lds16(const void* g, void* l) {
    __builtin_amdgcn_global_load_lds(
        (const __attribute__((address_space(1))) unsigned int*)g,
        (__attribute__((address_space(3))) unsigned int*)l,
        16, 0, 0);
}

#define WAITVM8()  do { asm volatile("s_waitcnt vmcnt(8)" ::: "memory"); __builtin_amdgcn_sched_barrier(0); } while (0)
#define WAITVM0()  do { asm volatile("s_waitcnt vmcnt(0)" ::: "memory"); __builtin_amdgcn_sched_barrier(0); } while (0)
#define WAITLGKM() do { asm volatile("s_waitcnt lgkmcnt(0)" ::: "memory"); __builtin_amdgcn_sched_barrier(0); } while (0)

// Stage one 128-col fp32 chunk (64 KB) wave-locally; per-lane SOURCE swizzle
// (16B slot u of col rho lands at LDS slot u^(rho&7)) -> conflict-free ds_reads.
// XOR moves 16B units within a 128B line -> global coalescing preserved.
__device__ __forceinline__ void issue_chunk_f32(const char* fbytes, int grow0,
                                                char* buf, int w, int lane) {
    #pragma unroll
    for (int i = 0; i < 8; ++i) {
        const int s   = i * 64 + lane;           // slot in this wave's 8KB region
        const int rho = s >> 5;                  // local col 0..15
        const int u   = (lane & 31) ^ (rho & 7); // source 16B chunk within the col
        const size_t src = (size_t)(grow0 + w * 16 + rho) * 512 + (size_t)u * 16;
        const int dst = w * 8192 + i * 1024 + lane * 16;   // linear LDS dest
        gl_lds16(fbytes + src, buf + dst);
    }
}

// ---------------- Kernel A: fused convert + MFMA gram + selection + intra ----------------
// 256 blocks x 512 threads (1 block/CU, 128 KB LDS). Block = 8 rows x ALL 1024 cols.
// 8 chunks of 128 cols staged as fp32 via swizzled-source DMA; bf16 conversion and
// exact fp32 norms computed in-register (no prep kernel, no bhi buffer).
__global__ __launch_bounds__(512, 1) void fused_kernel(
    const float* __restrict__ feat,
    const int* __restrict__ label1, const int* __restrict__ label2,
    float* __restrict__ partial)
{
    __shared__ __align__(16) char smem[131072];  // 2 x 64 KB ring; reused after loop

    const int rg    = blockIdx.x;            // 0..255
    const int half  = rg >> 7;
    const int arow0 = (rg & 127) * 8;
    const int aglob0 = half * BATCH + arow0;
    const int bglob0 = (half ^ 1) * BATCH;

    const int t = threadIdx.x;
    const int w = t >> 6, lane = t & 63;
    const int l15 = lane & 15, kg = lane >> 4;

    const int* labA = half ? label2 : label1;
    const int* labB = half ? label1 : label2;

    // ---- labels (issued first; retire before the DMA waits by in-order retirement) ----
    int lb[8];
    #pragma unroll
    for (int c = 0; c < 8; ++c) lb[c] = labB[c * 128 + w * 16 + l15];
    int la[4];
    #pragma unroll
    for (int r = 0; r < 4; ++r) la[r] = labA[arow0 + ((kg * 4 + r) & 7)];

    // ---- A-side: fp32 loads + in-register cvt + exact norm (consumed pre-prologue) ----
    const float* arow = feat + (size_t)(aglob0 + (l15 & 7)) * DIM;
    s16x8 ah[4];
    float naL = 0.0f;
    #pragma unroll
    for (int kt = 0; kt < 4; ++kt) {
        const float4 a0 = *reinterpret_cast<const float4*>(arow + kt * 32 + kg * 8);
        const float4 a1 = *reinterpret_cast<const float4*>(arow + kt * 32 + kg * 8 + 4);
        ah[kt] = cvt8(a0, a1, naL);
    }
    naL += __shfl_xor(naL, 16); naL += __shfl_xor(naL, 32);   // reduce over kg
    float na[4];
    #pragma unroll
    for (int r = 0; r < 4; ++r) na[r] = __shfl(naL, kg * 4 + r);

    // ---- prologue: DMA chunks 0,1 (fp32, swizzled source) ----
    const char* fbytes = reinterpret_cast<const char*>(feat);
    __builtin_amdgcn_sched_barrier(0);
    issue_chunk_f32(fbytes, bglob0 + 0 * 128, smem,         w, lane);
    issue_chunk_f32(fbytes, bglob0 + 1 * 128, smem + 65536, w, lane);
    WAITVM8();                      // chunk0 complete; chunk1 (8 newest) in flight

    float bpv[4], bnv[4]; int bpj[4], bnj[4];
    #pragma unroll
    for (int r = 0; r < 4; ++r) { bpv[r] = -1.0f; bpj[r] = 0x7fffffff; bnv[r] = FLT_MAX; bnj[r] = 0x7fffffff; }

    const int jl = w * 16 + l15;    // global col mod 128 (wave-local region)

    #pragma unroll
    for (int c = 0; c < 8; ++c) {
        const char* bufc = smem + (c & 1) * 65536;

        // ds_read this lane's 32 fp32 of col l15 (swizzled slots)
        float4 bv[8];
        #pragma unroll
        for (int kt = 0; kt < 4; ++kt) {
            const int u0 = kt * 8 + kg * 2;
            bv[2 * kt]     = *reinterpret_cast<const float4*>(
                bufc + w * 8192 + l15 * 512 + ((u0    ) ^ (l15 & 7)) * 16);
            bv[2 * kt + 1] = *reinterpret_cast<const float4*>(
                bufc + w * 8192 + l15 * 512 + ((u0 + 1) ^ (l15 & 7)) * 16);
        }
        WAITLGKM();                 // reads landed -> safe to overwrite this buffer
        if (c <= 5)
            issue_chunk_f32(fbytes, bglob0 + (c + 2) * 128,
                            smem + (c & 1) * 65536, w, lane);

        // in-register cvt + exact fp32 col norm
        float nbL = 0.0f;
        s16x8 bh[4];
        #pragma unroll
        for (int kt = 0; kt < 4; ++kt)
            bh[kt] = cvt8(bv[2 * kt], bv[2 * kt + 1], nbL);
        nbL += __shfl_xor(nbL, 16); nbL += __shfl_xor(nbL, 32);

        // MFMA (C/D: col=l15, row=kg*4+reg; rows>=8 duplicate rows 0..7)
        f32x4 acc = (f32x4){0.f, 0.f, 0.f, 0.f};
        #pragma unroll
        for (int kt = 0; kt < 4; ++kt)
            acc = __builtin_amdgcn_mfma_f32_16x16x32_bf16(ah[kt], bh[kt], acc, 0, 0, 0);

        // selection in d^2 domain; j = c*128 + jl ascending in c -> first occurrence kept
        const int jc = c * 128 + jl;
        #pragma unroll
        for (int r = 0; r < 4; ++r) {
            const float d2 = fmaxf(na[r] + nbL - 2.0f * acc[r], 0.0f);
            const bool same = (la[r] == lb[c]);
            const float pv = same ? d2 : 0.0f;
            const float nv = same ? FLT_MAX : d2;
            if (pv > bpv[r]) { bpv[r] = pv; bpj[r] = jc; }
            if (nv < bnv[r]) { bnv[r] = nv; bnj[r] = jc; }
        }

        if (c <= 5)      WAITVM8(); // next chunk complete; one more stays in flight
        else if (c == 6) WAITVM0(); // drain last chunk
    }

    // ---- in-wave reduce across the 16 lanes of each row group ----
    #pragma unroll
    for (int r = 0; r < 4; ++r) {
        #pragma unroll
        for (int m = 8; m > 0; m >>= 1) {
            const float opv = __shfl_xor(bpv[r], m); const int opj = __shfl_xor(bpj[r], m);
            if (opv > bpv[r] || (opv == bpv[r] && opj < bpj[r])) { bpv[r] = opv; bpj[r] = opj; }
            const float onv = __shfl_xor(bnv[r], m); const int onj = __shfl_xor(bnj[r], m);
            if (onv < bnv[r] || (onv == bnv[r] && onj < bnj[r])) { bnv[r] = onv; bnj[r] = onj; }
        }
    }

    __syncthreads();                // all waves done with LDS ring -> reuse smem

    float (*L_pv)[8] = (float(*)[8])(smem);
    int   (*L_pj)[8] = (int  (*)[8])(smem + 512);
    float (*L_nv)[8] = (float(*)[8])(smem + 1024);
    int   (*L_nj)[8] = (int  (*)[8])(smem + 1536);
    int*   s_pp = (int*)  (smem + 2048);
    int*   s_pn = (int*)  (smem + 2112);
    float* s_fp = (float*)(smem + 2176);
    float* s_cn = (float*)(smem + 2240);
    float* ls   = (float*)(smem + 2304);

    if (l15 == 0) {
        #pragma unroll
        for (int r = 0; r < 4; ++r) {
            const int rib = kg * 4 + r;     // rows 8..15 duplicate 0..7 (ignored below)
            L_pv[rib][w] = bpv[r]; L_pj[rib][w] = bpj[r];
            L_nv[rib][w] = bnv[r]; L_nj[rib][w] = bnj[r];
        }
    }
    __syncthreads();

    if (t < 8) {                    // merge 8 waves for the 8 real rows (tie-break on j)
        float pv = -1.0f; int pj = 0x7fffffff; float nv = FLT_MAX; int nj = 0x7fffffff;
        #pragma unroll
        for (int c = 0; c < 8; ++c) {
            const float v1 = L_pv[t][c]; const int j1 = L_pj[t][c];
            if (v1 > pv || (v1 == pv && j1 < pj)) { pv = v1; pj = j1; }
            const float v2 = L_nv[t][c]; const int j2 = L_nj[t][c];
            if (v2 < nv || (v2 == nv && j2 < nj)) { nv = v2; nj = j2; }
        }
        s_pp[t] = pj > (BATCH - 1) ? (BATCH - 1) : pj;
        s_pn[t] = nj > (BATCH - 1) ? (BATCH - 1) : nj;
        s_fp[t] = (pv > 0.0f) ? sqrtf(pv + EPSV) : 0.0f;   // no-positive row -> 0
        s_cn[t] = sqrtf(nv + EPSV);
    }
    __syncthreads();

    // ---- intra distances (exact fp32): 8 rows x 16 lanes ----
    if (t < 128) {
        const int g = t >> 4, sl = t & 15;
        const float* fB = feat + (size_t)(half ^ 1) * BATCH * DIM;  // b-side = f_intra
        const float4* x = reinterpret_cast<const float4*>(fB + (size_t)s_pp[g] * DIM + sl * 8);
        const float4* y = reinterpret_cast<const float4*>(fB + (size_t)s_pn[g] * DIM + sl * 8);
        const float4 x0 = x[0], x1 = x[1], y0 = y[0], y1 = y[1];
        float d, d2;
        d = x0.x - y0.x; d2  = d * d;  d = x0.y - y0.y; d2 += d * d;
        d = x0.z - y0.z; d2 += d * d;  d = x0.w - y0.w; d2 += d * d;
        d = x1.x - y1.x; d2 += d * d;  d = x1.y - y1.y; d2 += d * d;
        d = x1.z - y1.z; d2 += d * d;  d = x1.w - y1.w; d2 += d * d;
        d2 += __shfl_xor(d2, 1); d2 += __shfl_xor(d2, 2);
        d2 += __shfl_xor(d2, 4); d2 += __shfl_xor(d2, 8);
        if (sl == 0) {
            const float gd = sqrtf(d2 + EPSV);
            const float loss = fmaxf(s_fp[g] - s_cn[g] + MARGIN, 0.0f)
                             + LAMDA * fmaxf(INTRA_MARGIN - gd, 0.0f);
            ls[g] = loss * (1.0f / (float)BATCH);
        }
    }
    __syncthreads();

    if (t == 0) {
        float s = 0.0f;
        #pragma unroll
        for (int i = 0; i < 8; ++i) s += ls[i];
        partial[rg] = s;
    }
}

// ---------------- Kernel B: single-wave deterministic reduce of 256 partials ----------
__global__ __launch_bounds__(64) void reduce_kernel(
    const float* __restrict__ partial, float* __restrict__ out)
{
    const int t = threadIdx.x;
    float s = partial[t] + partial[t + 64] + partial[t + 128] + partial[t + 192];
    #pragma unroll
    for (int m = 32; m > 0; m >>= 1) s += __shfl_down(s, m);
    if (t == 0) out[0] = s;
}

extern "C" void kernel_launch(void* const* d_in, const int* in_sizes, int n_in,
                              void* d_out, int out_size, void* d_ws, size_t ws_size,
                              hipStream_t stream) {
    const float* feat   = (const float*)d_in[0];
    const int*   label1 = (const int*)d_in[1];
    const int*   label2 = (const int*)d_in[2];
    float* out = (float*)d_out;

    float* partial = (float*)d_ws;   // 256 floats

    fused_kernel<<<dim3(256), dim3(512), 0, stream>>>(feat, label1, label2, partial);
    reduce_kernel<<<dim3(1), dim3(64), 0, stream>>>(partial, out);
}

// Round 15
// 20.753 us; speedup vs baseline: 1.1066x; 1.1066x over previous
//
#include <hip/hip_runtime.h>
#include <math.h>
#include <float.h>

#define BATCH 1024
#define DIM 128
#define EPSV 1e-12f
#define MARGIN 0.5f
#define INTRA_MARGIN 0.1f
#define LAMDA 0.5f

typedef __attribute__((ext_vector_type(8))) short s16x8;   // 8 bf16 (4 VGPRs)
typedef __attribute__((ext_vector_type(4))) float f32x4;   // MFMA C/D

__device__ __forceinline__ ushort f2bf(float f) {          // RNE fp32 -> bf16
    unsigned u = __float_as_uint(f);
    return (ushort)((u + 0x7fffu + ((u >> 16) & 1u)) >> 16);
}

// async global->LDS, 16B per lane (dest = wave-uniform base + lane*16)
__device__ __forceinline__ void gl_lds16(const void* g, void* l) {
    __builtin_amdgcn_global_load_lds(
        (const __attribute__((address_space(1))) unsigned int*)g,
        (__attribute__((address_space(3))) unsigned int*)l,
        16, 0, 0);
}

#define WAITVM8()  do { asm volatile("s_waitcnt vmcnt(8)" ::: "memory"); __builtin_amdgcn_sched_barrier(0); } while (0)
#define WAITVM4()  do { asm volatile("s_waitcnt vmcnt(4)" ::: "memory"); __builtin_amdgcn_sched_barrier(0); } while (0)
#define WAITVM0()  do { asm volatile("s_waitcnt vmcnt(0)" ::: "memory"); __builtin_amdgcn_sched_barrier(0); } while (0)

// ---------------- Kernel A: feat -> bf16 (XOR-swizzled) + fp32 row norms ----------------
// Swizzle: 16B chunk j of row r stored at chunk index (j ^ (r&7)) within the row.
__global__ __launch_bounds__(256) void prep_kernel(
    const float* __restrict__ feat, ushort* __restrict__ bhi,
    float* __restrict__ norm2)
{
    const int t = threadIdx.x;
    const int gt  = blockIdx.x * 256 + t;  // 0..32767
    const int row = gt >> 4, seg = gt & 15;
    const float4* p = reinterpret_cast<const float4*>(feat + (size_t)row * DIM + seg * 8);
    const float4 a = p[0], b = p[1];
    const float v[8] = {a.x, a.y, a.z, a.w, b.x, b.y, b.z, b.w};
    ushort h[8];
    float n = 0.0f;
    #pragma unroll
    for (int e = 0; e < 8; ++e) {
        h[e] = f2bf(v[e]);
        n = fmaf(v[e], v[e], n);
    }
    uint4 uh;
    uh.x = (uint)h[0] | ((uint)h[1] << 16); uh.y = (uint)h[2] | ((uint)h[3] << 16);
    uh.z = (uint)h[4] | ((uint)h[5] << 16); uh.w = (uint)h[6] | ((uint)h[7] << 16);
    reinterpret_cast<uint4*>(bhi)[row * 16 + (seg ^ (row & 7))] = uh;   // swizzled chunk
    n += __shfl_xor(n, 1); n += __shfl_xor(n, 2);
    n += __shfl_xor(n, 4); n += __shfl_xor(n, 8);
    if ((t & 15) == 0) norm2[row] = n;
}

__device__ __forceinline__ void issue_chunk(const char* bbytes, size_t gbase,
                                            char* buf, int w, int lane) {
    #pragma unroll
    for (int i = 0; i < 4; ++i) {
        const int o = w * 4096 + i * 1024 + lane * 16;
        gl_lds16(bbytes + gbase + o, buf + o);
    }
}

// ---------------- Kernel B: deep-pipelined LDS-staged MFMA gram + selection + intra ----
// 256 blocks x 512 threads (1 block/CU, 128 KB LDS). Block = 8 rows x ALL 1024 cols.
// 8 chunks of 128 cols; 4 x 32 KB LDS ring; wave-local staging (wave w stages and reads
// only cols [w*16, +16) of each chunk) -> NO barriers, NO lgkm guard (overwrite target
// is 4 chunks old; compiler's lgkmcnt waits before the MFMAs already drained its reads).
// Counted vmcnt(8): 2-3 chunks in flight, ~2 iterations of latency cover (T3/T4).
__global__ __launch_bounds__(512, 1) void gemm_kernel(
    const ushort* __restrict__ bhi, const float* __restrict__ norm2,
    const float* __restrict__ feat,
    const int* __restrict__ label1, const int* __restrict__ label2,
    float* __restrict__ partial)
{
    __shared__ __align__(16) char smem[131072];  // 4 x 32 KB ring; reused after loop

    const int rg    = blockIdx.x;            // 0..255
    const int half  = rg >> 7;
    const int arow0 = (rg & 127) * 8;
    const int aglob0 = half * BATCH + arow0;
    const int bglob0 = (half ^ 1) * BATCH;

    const int t = threadIdx.x;
    const int w = t >> 6, lane = t & 63;
    const int l15 = lane & 15, kg = lane >> 4;

    const int* labA = half ? label2 : label1;
    const int* labB = half ? label1 : label2;

    // ---- scalar-side loads (retire before the prologue vmcnt wait) ----
    float nb[8]; int lb[8];
    #pragma unroll
    for (int c = 0; c < 8; ++c) {
        const int jc = c * 128 + w * 16 + l15;
        nb[c] = norm2[bglob0 + jc];
        lb[c] = labB[jc];
    }
    float na[4]; int la[4];
    #pragma unroll
    for (int r = 0; r < 4; ++r) {
        const int rr = (kg * 4 + r) & 7;
        na[r] = norm2[aglob0 + rr];
        la[r] = labA[arow0 + rr];
    }

    // ---- A fragments from global (pre-swizzled addresses); rows duplicated via l15&7 ----
    s16x8 ah[4];
    const size_t abase = (size_t)(aglob0 + (l15 & 7)) * DIM;
    #pragma unroll
    for (int kt = 0; kt < 4; ++kt) {
        const int kh = (kt * 32 + kg * 8) ^ ((l15 & 7) << 3);
        ah[kt] = *reinterpret_cast<const s16x8*>(bhi + abase + kh);
    }

    // ---- prologue: DMA chunks 0,1,2 into ring slots 0,1,2 ----
    const char* bbytes = reinterpret_cast<const char*>(bhi);
    issue_chunk(bbytes, (size_t)(bglob0 + 0 * 128) * 256, smem + 0 * 32768, w, lane);
    issue_chunk(bbytes, (size_t)(bglob0 + 1 * 128) * 256, smem + 1 * 32768, w, lane);
    issue_chunk(bbytes, (size_t)(bglob0 + 2 * 128) * 256, smem + 2 * 32768, w, lane);
    WAITVM8();                      // scalars+A+chunk0 retired; chunks 1,2 in flight

    float bpv[4], bnv[4]; int bpj[4], bnj[4];
    #pragma unroll
    for (int r = 0; r < 4; ++r) { bpv[r] = -1.0f; bpj[r] = 0x7fffffff; bnv[r] = FLT_MAX; bnj[r] = 0x7fffffff; }

    const int jl = w * 16 + l15;    // local col within chunk (wave-local region)

    #pragma unroll
    for (int c = 0; c < 8; ++c) {
        const ushort* bufc = reinterpret_cast<const ushort*>(smem + (c & 3) * 32768);

        // ds_read the 4 B-fragments for this chunk (own wave's staged cols)
        s16x8 bh[4];
        #pragma unroll
        for (int kt = 0; kt < 4; ++kt) {
            const int kh = (kt * 32 + kg * 8) ^ ((l15 & 7) << 3);
            bh[kt] = *reinterpret_cast<const s16x8*>(bufc + jl * DIM + kh);
        }
        if (c <= 4)                 // prefetch chunk c+3 into slot (c+3)&3 (= chunk c-1's)
            issue_chunk(bbytes, (size_t)(bglob0 + (c + 3) * 128) * 256,
                        smem + ((c + 3) & 3) * 32768, w, lane);

        // MFMA (C/D: col=l15, row=kg*4+reg; rows>=8 duplicate rows 0..7)
        f32x4 acc = (f32x4){0.f, 0.f, 0.f, 0.f};
        #pragma unroll
        for (int kt = 0; kt < 4; ++kt)
            acc = __builtin_amdgcn_mfma_f32_16x16x32_bf16(ah[kt], bh[kt], acc, 0, 0, 0);

        // selection in d^2 domain; j = c*128 + jl ascending in c -> first occurrence kept
        const int jc = c * 128 + jl;
        #pragma unroll
        for (int r = 0; r < 4; ++r) {
            const float d2 = fmaxf(na[r] + nb[c] - 2.0f * acc[r], 0.0f);
            const bool same = (la[r] == lb[c]);
            const float pv = same ? d2 : 0.0f;
            const float nv = same ? FLT_MAX : d2;
            if (pv > bpv[r]) { bpv[r] = pv; bpj[r] = jc; }
            if (nv < bnv[r]) { bnv[r] = nv; bnj[r] = jc; }
        }

        // retire the next chunk's DMA: end of iter c -> chunk c+1 complete
        if (c <= 4)      WAITVM8();
        else if (c == 5) WAITVM4();
        else if (c == 6) WAITVM0();
    }

    // ---- in-wave reduce across the 16 lanes of each row group ----
    #pragma unroll
    for (int r = 0; r < 4; ++r) {
        #pragma unroll
        for (int m = 8; m > 0; m >>= 1) {
            const float opv = __shfl_xor(bpv[r], m); const int opj = __shfl_xor(bpj[r], m);
            if (opv > bpv[r] || (opv == bpv[r] && opj < bpj[r])) { bpv[r] = opv; bpj[r] = opj; }
            const float onv = __shfl_xor(bnv[r], m); const int onj = __shfl_xor(bnj[r], m);
            if (onv < bnv[r] || (onv == bnv[r] && onj < bnj[r])) { bnv[r] = onv; bnj[r] = onj; }
        }
    }

    __syncthreads();                // all waves done with LDS ring -> reuse smem

    float (*L_pv)[8] = (float(*)[8])(smem);
    int   (*L_pj)[8] = (int  (*)[8])(smem + 512);
    float (*L_nv)[8] = (float(*)[8])(smem + 1024);
    int   (*L_nj)[8] = (int  (*)[8])(smem + 1536);
    int*   s_pp = (int*)  (smem + 2048);
    int*   s_pn = (int*)  (smem + 2112);
    float* s_fp = (float*)(smem + 2176);
    float* s_cn = (float*)(smem + 2240);
    float* ls   = (float*)(smem + 2304);

    if (l15 == 0) {
        #pragma unroll
        for (int r = 0; r < 4; ++r) {
            const int rib = kg * 4 + r;     // rows 8..15 duplicate 0..7 (ignored below)
            L_pv[rib][w] = bpv[r]; L_pj[rib][w] = bpj[r];
            L_nv[rib][w] = bnv[r]; L_nj[rib][w] = bnj[r];
        }
    }
    __syncthreads();

    if (t < 8) {                    // merge 8 waves for the 8 real rows (tie-break on j)
        float pv = -1.0f; int pj = 0x7fffffff; float nv = FLT_MAX; int nj = 0x7fffffff;
        #pragma unroll
        for (int c = 0; c < 8; ++c) {
            const float v1 = L_pv[t][c]; const int j1 = L_pj[t][c];
            if (v1 > pv || (v1 == pv && j1 < pj)) { pv = v1; pj = j1; }
            const float v2 = L_nv[t][c]; const int j2 = L_nj[t][c];
            if (v2 < nv || (v2 == nv && j2 < nj)) { nv = v2; nj = j2; }
        }
        s_pp[t] = pj > (BATCH - 1) ? (BATCH - 1) : pj;
        s_pn[t] = nj > (BATCH - 1) ? (BATCH - 1) : nj;
        s_fp[t] = (pv > 0.0f) ? sqrtf(pv + EPSV) : 0.0f;   // no-positive row -> 0
        s_cn[t] = sqrtf(nv + EPSV);
    }
    __syncthreads();

    // ---- intra distances (exact fp32): 8 rows x 16 lanes ----
    if (t < 128) {
        const int g = t >> 4, sl = t & 15;
        const float* fB = feat + (size_t)(half ^ 1) * BATCH * DIM;  // b-side = f_intra
        const float4* x = reinterpret_cast<const float4*>(fB + (size_t)s_pp[g] * DIM + sl * 8);
        const float4* y = reinterpret_cast<const float4*>(fB + (size_t)s_pn[g] * DIM + sl * 8);
        const float4 x0 = x[0], x1 = x[1], y0 = y[0], y1 = y[1];
        float d, d2;
        d = x0.x - y0.x; d2  = d * d;  d = x0.y - y0.y; d2 += d * d;
        d = x0.z - y0.z; d2 += d * d;  d = x0.w - y0.w; d2 += d * d;
        d = x1.x - y1.x; d2 += d * d;  d = x1.y - y1.y; d2 += d * d;
        d = x1.z - y1.z; d2 += d * d;  d = x1.w - y1.w; d2 += d * d;
        d2 += __shfl_xor(d2, 1); d2 += __shfl_xor(d2, 2);
        d2 += __shfl_xor(d2, 4); d2 += __shfl_xor(d2, 8);
        if (sl == 0) {
            const float gd = sqrtf(d2 + EPSV);
            const float loss = fmaxf(s_fp[g] - s_cn[g] + MARGIN, 0.0f)
                             + LAMDA * fmaxf(INTRA_MARGIN - gd, 0.0f);
            ls[g] = loss * (1.0f / (float)BATCH);
        }
    }
    __syncthreads();

    if (t == 0) {
        float s = 0.0f;
        #pragma unroll
        for (int i = 0; i < 8; ++i) s += ls[i];
        partial[rg] = s;
    }
}

// ---------------- Kernel C: single-wave deterministic reduce of 256 partials ----------
__global__ __launch_bounds__(64) void reduce_kernel(
    const float* __restrict__ partial, float* __restrict__ out)
{
    const int t = threadIdx.x;
    float s = partial[t] + partial[t + 64] + partial[t + 128] + partial[t + 192];
    #pragma unroll
    for (int m = 32; m > 0; m >>= 1) s += __shfl_down(s, m);
    if (t == 0) out[0] = s;
}

extern "C" void kernel_launch(void* const* d_in, const int* in_sizes, int n_in,
                              void* d_out, int out_size, void* d_ws, size_t ws_size,
                              hipStream_t stream) {
    const float* feat   = (const float*)d_in[0];
    const int*   label1 = (const int*)d_in[1];
    const int*   label2 = (const int*)d_in[2];
    float* out = (float*)d_out;

    char* ws = (char*)d_ws;
    float*  partial = (float*)(ws);                        // 1 KB
    ushort* bhi     = (ushort*)(ws + 4096);                // 512 KB (pre-swizzled)
    float*  norm2   = (float*)(ws + 4096 + 512 * 1024);    // 8 KB

    prep_kernel<<<dim3(128), dim3(256), 0, stream>>>(feat, bhi, norm2);
    gemm_kernel<<<dim3(256), dim3(512), 0, stream>>>(
        bhi, norm2, feat, label1, label2, partial);
    reduce_kernel<<<dim3(1), dim3(64), 0, stream>>>(partial, out);
}